// Round 10
// baseline (312.901 us; speedup 1.0000x reference)
//
#include <hip/hip_runtime.h>
#include <hip/hip_fp16.h>

// SparseEncoder4D R10: 3 plain kernels (R9's cooperative single-kernel never
// launched — silent hipLaunchCooperativeKernel failure; reverted).
//  k_h1b: LDS-staged mask -> layer1 h1 fp16 (feats==ones) + bitsT (3x32-bit
//         chunk words) + Btab (MFMA B-frags, pad rows 0) + scatter ELECTION
//         atomicMax(cell, n+1) (0xAA poison is negative, memset-0 loses too).
//  k_h2m: layer2+head MFMA gather-GEMM. 256 rows/block, 4 row-groups/wave
//         (4 independent MFMA chains -> 4x gathers in flight vs R7's 69us),
//         idx sentinelized at staging (mask folded), NP=2 L2-resident slice
//         passes (R7: FETCH 35 MB; R8 falsified NP=1), exec-masked gathers.
//  k_fin: dense election int -> float (R8-proven; replaces memset+scatter).

#define KK 81
#define CH 8
#define NP 2      // slice passes; 1.2 MB h1 slice stays L2-resident under streams
#define NS 21     // K-slices of 32: chunks contribute 8+8+5
#define TT 4
#define ZZ 32
#define YY 256
#define XX 256

typedef __attribute__((ext_vector_type(8))) _Float16 half8;  // 16 B
typedef __attribute__((ext_vector_type(4))) float f32x4;

__device__ __forceinline__ int cell_of(const int* coords, const int* batch, int n) {
    int4 c = *(const int4*)(coords + 4 * n);  // (x, y, z, t)
    int b = batch[n];
    return (((b * TT + c.w) * ZZ + c.z) * YY + c.y) * XX + c.x;
}

// ---------------- k_h1b ------------------------------------------------------
__global__ __launch_bounds__(256) void k_h1b(const float* __restrict__ w1,
                                             const float* __restrict__ w2,
                                             const int* __restrict__ nbr_mask,
                                             const int* __restrict__ coords,
                                             const int* __restrict__ batch,
                                             half8* __restrict__ h1,
                                             unsigned* __restrict__ bitsT,
                                             half8* __restrict__ Btab,
                                             int* elect,
                                             int n_total, int npad) {
    __shared__ int ls[256 * 33];  // 33.8 KB (max chunk stride 33)
    const int tid = threadIdx.x;
    const int n0 = blockIdx.x * 256;
    const int n = n0 + tid;

    if (blockIdx.x == 0 && tid == 0) {   // zero row: dummy gather target
        half8 z = {(_Float16)0.f, (_Float16)0.f, (_Float16)0.f, (_Float16)0.f,
                   (_Float16)0.f, (_Float16)0.f, (_Float16)0.f, (_Float16)0.f};
        h1[n_total] = z;
    }
    if (blockIdx.x < NS && tid < 64) {   // Btab: B-frag slice s, lane tid
        int s = blockIdx.x, q = tid >> 4, d = tid & 15;
        int kk = 4 * s + q;              // conv-k; >= 81 -> zero pad row
        half8 b;
#pragma unroll
        for (int j = 0; j < CH; j++)
            b[j] = (d < CH && kk < KK) ? (_Float16)w2[(kk * CH + j) * CH + d]
                                       : (_Float16)0.f;
        Btab[s * 64 + tid] = b;
    }

    float acc[CH] = {0.f, 0.f, 0.f, 0.f, 0.f, 0.f, 0.f, 0.f};
    unsigned cb[3];
#pragma unroll
    for (int ch = 0; ch < 3; ch++) {
        const int kb = ch * 32;
        const int kcnt = (ch == 2) ? 17 : 32;   // valid conv-k this chunk
        const int stride = kcnt + 1;
        for (int j = 0; j < kcnt; j++) {        // coalesced flat staging
            int i = tid + j * 256;
            int r = i / kcnt, c = i - r * kcnt;
            int srcn = n0 + r; if (srcn >= n_total) srcn = n_total - 1;
            ls[r * stride + c] = nbr_mask[(long)srcn * KK + kb + c];
        }
        __syncthreads();
        unsigned cbits = 0;
        const int* row = ls + tid * stride;     // (tid+c)%32 banks: 2-way, free
        for (int c = 0; c < kcnt; c++) {
            int mm = row[c];
            cbits |= (unsigned)(mm & 1) << c;
            float fm = (float)mm;
            const float* wp = w1 + (kb + c) * CH;  // wave-uniform s_load
#pragma unroll
            for (int d = 0; d < CH; d++) acc[d] += fm * wp[d];
        }
        cb[ch] = cbits;
        __syncthreads();
    }

    if (n < n_total) {
        half8 r;
#pragma unroll
        for (int c = 0; c < CH; c++) r[c] = (_Float16)fmaxf(acc[c], 0.f);
        h1[n] = r;
        bitsT[n]            = cb[0];
        bitsT[npad + n]     = cb[1];
        bitsT[2 * npad + n] = cb[2];
        // last-write-wins = max n (numpy order); poison (negative) / 0 lose.
        atomicMax(elect + cell_of(coords, batch, n), n + 1);
    }
}

// ---------------- k_h2m: MFMA gather-GEMM -----------------------------------
// 256 rows/block; wave owns 64 rows as 4 groups of 16 (4 MFMA chains).
__global__ __launch_bounds__(256) void k_h2m(const half8* __restrict__ h1,
                                             const half8* __restrict__ Btab,
                                             const int* __restrict__ nbr_idx,
                                             const unsigned* __restrict__ bitsT,
                                             const float* __restrict__ w_out,
                                             float* __restrict__ outf,
                                             int n_total, int npad) {
    __shared__ unsigned ls[256 * 34];   // 34.8 KB idx tile (stride kslots+2)
    __shared__ unsigned sbw[256];       // this chunk's bit-words
    const int tid = threadIdx.x;
    const int n0 = blockIdx.x * 256;
    const int lane = tid & 63, wid = tid >> 6;
    const int m = lane & 15, q = lane >> 4;
    const int slice = (n_total + NP - 1) / NP;
    const unsigned uslice = (unsigned)slice;
    const half8 hz = {(_Float16)0.f, (_Float16)0.f, (_Float16)0.f, (_Float16)0.f,
                      (_Float16)0.f, (_Float16)0.f, (_Float16)0.f, (_Float16)0.f};

    f32x4 accg[4];
#pragma unroll
    for (int g = 0; g < 4; g++) accg[g] = (f32x4){0.f, 0.f, 0.f, 0.f};

    int sbase = 0;
#pragma unroll
    for (int ch = 0; ch < 3; ch++) {
        const int kb = ch * 32;
        const int kv = (ch == 2) ? 17 : 32;      // valid conv-k
        const int kslots = (ch == 2) ? 20 : 32;  // padded to 4*nsl
        const int nsl = kslots >> 2;
        const int stride = kslots + 2;
        {   // bits for these 256 rows, this chunk
            int sn = n0 + tid;
            sbw[tid] = (sn < n_total) ? bitsT[(long)ch * npad + sn] : 0u;
        }
        __syncthreads();
        // stage sentinelized idx (mask folded; OOR/pad -> ~0)
        for (int j = 0; j < kslots; j++) {
            int i = tid + j * 256;
            int r = i / kslots, c = i - r * kslots;
            int sn = n0 + r;
            unsigned v = 0xFFFFFFFFu;
            if (c < kv && sn < n_total && ((sbw[r] >> c) & 1u))
                v = (unsigned)nbr_idx[(long)sn * KK + kb + c];
            ls[r * stride + c] = v;
        }
        __syncthreads();
        for (int p = 0; p < NP; p++) {
            unsigned lo = (unsigned)(p * slice);
#pragma unroll
            for (int g = 0; g < 4; g++) {
                // bank (34m+4s+q)%32 = (2m+4s+q)%32: <=2-way, free
                const unsigned* rowp = ls + (wid * 64 + g * 16 + m) * stride;
                for (int s = 0; s < nsl; s++) {
                    unsigned ix = rowp[4 * s + q];
                    half8 a = hz;
                    if (ix - lo < uslice)        // exec-masked: only active
                        a = h1[ix];              //   lanes issue the gather
                    half8 b = Btab[(sbase + s) * 64 + lane];
                    accg[g] = __builtin_amdgcn_mfma_f32_16x16x32_f16(
                        a, b, accg[g], 0, 0, 0);
                }
            }
        }
        __syncthreads();
        sbase += nsl;
    }

    // C/D: col(lane&15)=d, row=q*4+reg (n). relu * w_out, sum 16-lane cols.
    float wo = (m < CH) ? w_out[m] : 0.f;
#pragma unroll
    for (int g = 0; g < 4; g++) {
        float v0 = fmaxf(accg[g][0], 0.f) * wo;
        float v1 = fmaxf(accg[g][1], 0.f) * wo;
        float v2 = fmaxf(accg[g][2], 0.f) * wo;
        float v3 = fmaxf(accg[g][3], 0.f) * wo;
#pragma unroll
        for (int off = 1; off < 16; off <<= 1) {
            v0 += __shfl_xor(v0, off, 16);
            v1 += __shfl_xor(v1, off, 16);
            v2 += __shfl_xor(v2, off, 16);
            v3 += __shfl_xor(v3, off, 16);
        }
        if (m == 0) {
            int gn = n0 + wid * 64 + g * 16 + q * 4;
            if (gn + 0 < n_total) outf[gn + 0] = v0;
            if (gn + 1 < n_total) outf[gn + 1] = v1;
            if (gn + 2 < n_total) outf[gn + 2] = v2;
            if (gn + 3 < n_total) outf[gn + 3] = v3;
        }
    }
}

// ---------------- k_fin: dense election -> float ----------------------------
__global__ __launch_bounds__(256) void k_fin(const float* __restrict__ outf,
                                             int* cells, float* cellsf,
                                             int n_cells4, int n_total) {
    int i = blockIdx.x * blockDim.x + threadIdx.x;
    if (i >= n_cells4) return;
    int4 v = ((const int4*)cells)[i];
    float4 r;
    r.x = (v.x >= 1 && v.x <= n_total) ? outf[v.x - 1] : 0.f;
    r.y = (v.y >= 1 && v.y <= n_total) ? outf[v.y - 1] : 0.f;
    r.z = (v.z >= 1 && v.z <= n_total) ? outf[v.z - 1] : 0.f;
    r.w = (v.w >= 1 && v.w <= n_total) ? outf[v.w - 1] : 0.f;
    ((float4*)cellsf)[i] = r;
}

extern "C" void kernel_launch(void* const* d_in, const int* in_sizes, int n_in,
                              void* d_out, int out_size, void* d_ws, size_t ws_size,
                              hipStream_t stream) {
    const float* w1       = (const float*)d_in[1];
    const float* w2       = (const float*)d_in[2];
    const float* w_out    = (const float*)d_in[3];
    const int*   nbr_idx  = (const int*)d_in[4];
    const int*   nbr_mask = (const int*)d_in[5];
    const int*   coords   = (const int*)d_in[6];
    const int*   batch    = (const int*)d_in[7];

    int n_total = in_sizes[0];
    int npad = (n_total + 63) & ~63;
    int nc4 = out_size / 4;

    // ws: h1 (N+1 half8, 2.4 MB) | bitsT (3*npad u32, 1.8 MB) | outf (N f32)
    //     | Btab (NS*64 half8, 21.5 KB)
    half8*    h1    = (half8*)d_ws;
    unsigned* bitsT = (unsigned*)((char*)d_ws + (size_t)(n_total + 1) * sizeof(half8));
    float*    outf  = (float*)((char*)bitsT + (size_t)3 * npad * sizeof(unsigned));
    half8*    Btab  = (half8*)(outf + npad);
    float*    out   = (float*)d_out;

    int nb = (n_total + 255) / 256;
    k_h1b<<<nb, 256, 0, stream>>>(w1, w2, nbr_mask, coords, batch,
                                  h1, bitsT, Btab, (int*)out, n_total, npad);
    k_h2m<<<nb, 256, 0, stream>>>(h1, Btab, nbr_idx, bitsT, w_out, outf,
                                  n_total, npad);
    k_fin<<<(nc4 + 255) / 256, 256, 0, stream>>>(outf, (int*)out, out, nc4, n_total);
}

// Round 11
// 235.698 us; speedup vs baseline: 1.3275x; 1.3275x over previous
//
#include <hip/hip_runtime.h>
#include <hip/hip_fp16.h>

// SparseEncoder4D R11. Lesson from R10: for the latency-bound gather-GEMM,
// waves/CU from a big grid beat per-wave ILP — 4 row-groups/wave shrank the
// grid 4x and regressed 69->148us. R11:
//  k_h1b v2: 64-row blocks (2344 blocks), one-shot LDS mask stage (stride 85,
//            2-way banks), 4 threads/row k-quarters (quarter==wave -> w1 stays
//            wave-uniform), LDS partial reduction; wave0 writes h1 fp16,
//            bitsT chunk words, election atomicMax(cell, n+1).
//  k_h2m:    R7-proven structure VERBATIM (64 rows/block, 16 rows/wave, one
//            MFMA chain, NP=2 L2-resident slice passes, exec-masked gathers,
//            21.5 KB LDS, 36 VGPR -> 69us, FETCH 35 MB).
//  k_fin:    dense election -> float (R8-proven; replaces memset+scatter).

#define KK 81
#define CH 8
#define NP 2      // slice passes; 1.2 MB h1 slice stays L2-resident (R7-proven)
#define NS 21     // K-slices of 32 (21*32 = 672 >= 648)
#define KP 84     // padded conv-k slots (4 per slice)
#define TT 4
#define ZZ 32
#define YY 256
#define XX 256

typedef __attribute__((ext_vector_type(8))) _Float16 half8;  // 16 B
typedef __attribute__((ext_vector_type(4))) float f32x4;

__device__ __forceinline__ int cell_of(const int* coords, const int* batch, int n) {
    int4 c = *(const int4*)(coords + 4 * n);  // (x, y, z, t)
    int b = batch[n];
    return (((b * TT + c.w) * ZZ + c.z) * YY + c.y) * XX + c.x;
}

// ---------------- k_h1b: layer1 (feats==ones) + bits + election -------------
// 64 rows/block, 256 threads. LDS: 64 x 85 ints staging, then reused for
// partial reduction (2048 f32 + 256 u32 < 5440 words).
__global__ __launch_bounds__(256) void k_h1b(const float* __restrict__ w1,
                                             const float* __restrict__ w2,
                                             const int* __restrict__ nbr_mask,
                                             const int* __restrict__ coords,
                                             const int* __restrict__ batch,
                                             half8* __restrict__ h1,
                                             unsigned* __restrict__ bitsT,
                                             half8* __restrict__ Btab,
                                             int* elect,
                                             int n_total, int npad) {
    __shared__ int ls[64 * 85];          // 21.76 KB
    const int tid = threadIdx.x;
    const int n0 = blockIdx.x * 64;

    if (blockIdx.x == 0 && tid == 64) {  // zero row: dummy gather target
        half8 z = {(_Float16)0.f, (_Float16)0.f, (_Float16)0.f, (_Float16)0.f,
                   (_Float16)0.f, (_Float16)0.f, (_Float16)0.f, (_Float16)0.f};
        h1[n_total] = z;
    }
    if (blockIdx.x < NS && tid < 64) {   // Btab: MFMA B-frag, pad rows zero
        int s = blockIdx.x, q = tid >> 4, d = tid & 15;
        int kk = 4 * s + q;
        half8 b;
#pragma unroll
        for (int j = 0; j < CH; j++)
            b[j] = (d < CH && kk < KK) ? (_Float16)w2[(kk * CH + j) * CH + d]
                                       : (_Float16)0.f;
        Btab[s * 64 + tid] = b;
    }

    // stage 64 x 81 masks, flat coalesced (5184 = 20*256 + 64)
    for (int j = 0; j < 21; j++) {
        int i = tid + j * 256;
        if (i < 64 * KK) {
            int r = i / KK, c = i - r * KK;
            int srcn = n0 + r; if (srcn >= n_total) srcn = n_total - 1;
            ls[r * 85 + c] = nbr_mask[(long)srcn * KK + c];
        }
    }
    __syncthreads();

    // 4 threads/row: quarter qq = wave id (w1 row k stays wave-uniform)
    const int r = tid & 63, qq = tid >> 6;
    const int kbase = 21 * qq;
    const int kcnt = (qq == 3) ? 18 : 21;
    float acc[CH] = {0.f, 0.f, 0.f, 0.f, 0.f, 0.f, 0.f, 0.f};
    unsigned pb = 0;
    for (int c2 = 0; c2 < kcnt; c2++) {
        int k = kbase + c2;
        int mm = ls[r * 85 + k];          // (21r+k)%32: 2-way, free
        pb |= (unsigned)(mm & 1) << c2;
        float fm = (float)mm;
        const float* wp = w1 + k * CH;    // wave-uniform s_load
#pragma unroll
        for (int d = 0; d < CH; d++) acc[d] += fm * wp[d];
    }
    __syncthreads();
    // partials -> LDS (reuse): acc at lsf[(qq*64+r)*8+d], bits at lsb[qq*64+r]
    float* lsf = (float*)ls;
    unsigned* lsb = (unsigned*)ls + 2048;
#pragma unroll
    for (int d = 0; d < CH; d++) lsf[(qq * 64 + r) * CH + d] = acc[d];
    lsb[qq * 64 + r] = pb;
    __syncthreads();

    if (tid < 64) {
        int n = n0 + tid;
        if (n < n_total) {
            float s[CH];
#pragma unroll
            for (int d = 0; d < CH; d++)
                s[d] = lsf[tid * CH + d] + lsf[(64 + tid) * CH + d] +
                       lsf[(128 + tid) * CH + d] + lsf[(192 + tid) * CH + d];
            half8 rr;
#pragma unroll
            for (int d = 0; d < CH; d++) rr[d] = (_Float16)fmaxf(s[d], 0.f);
            h1[n] = rr;
            unsigned p0 = lsb[tid], p1 = lsb[64 + tid],
                     p2 = lsb[128 + tid], p3 = lsb[192 + tid];
            unsigned long long U = (unsigned long long)p0 |
                                   ((unsigned long long)p1 << 21) |
                                   ((unsigned long long)p2 << 42);
            bitsT[n]            = (unsigned)U;                       // k 0..31
            bitsT[npad + n]     = (unsigned)(U >> 32) | ((p3 & 1u) << 31); // 32..63
            bitsT[2 * npad + n] = p3 >> 1;                           // 64..80
            // last-write-wins = max n; 0xAA poison (negative) / 0 both lose
            atomicMax(elect + cell_of(coords, batch, n), n + 1);
        }
    }
}

// ---------------- k_h2m: MFMA gather-GEMM (R7-proven, 69us) -----------------
// 64 rows/block, 4 waves; wave owns 16 rows, one MFMA chain.
__global__ __launch_bounds__(256) void k_h2m(const half8* __restrict__ h1,
                                             const half8* __restrict__ Btab,
                                             const int* __restrict__ nbr_idx,
                                             const unsigned* __restrict__ bitsT,
                                             const float* __restrict__ w_out,
                                             float* __restrict__ outf,
                                             int n_total, int npad) {
    __shared__ unsigned sidx[64 * KP];   // 21.5 KB sentinelized idx
    __shared__ unsigned sbits[3 * 64];
    const int tid = threadIdx.x;
    const int n0 = blockIdx.x * 64;

    if (tid < 192) {
        int w = tid >> 6, r = tid & 63;
        int sn = n0 + r;
        sbits[w * 64 + r] = (sn < n_total) ? bitsT[(long)w * npad + sn] : 0u;
    }
    __syncthreads();

    // stage masked idx: 64 x 84 = 5376 = 21*256 (coalesced over c)
#pragma unroll
    for (int j = 0; j < 21; j++) {
        int i = tid + j * 256;
        int r = i / KP, c = i - r * KP;
        unsigned v = 0xFFFFFFFFu;
        int sn = n0 + r;
        if (c < KK && sn < n_total) {
            unsigned bit = (sbits[(c >> 5) * 64 + r] >> (c & 31)) & 1u;
            if (bit) v = (unsigned)nbr_idx[(long)sn * KK + c];
        }
        sidx[i] = v;
    }
    __syncthreads();

    const int lane = tid & 63, wid = tid >> 6;
    const int m = lane & 15, q = lane >> 4;
    const unsigned* myidx = sidx + (wid * 16 + m) * KP;
    const int slice = (n_total + NP - 1) / NP;
    const unsigned uslice = (unsigned)slice;

    f32x4 acc = {0.f, 0.f, 0.f, 0.f};
    for (int p = 0; p < NP; p++) {
        unsigned lo = (unsigned)(p * slice);
#pragma unroll 3
        for (int s = 0; s < NS; s++) {
            unsigned ix = myidx[4 * s + q];
            half8 a = {(_Float16)0.f, (_Float16)0.f, (_Float16)0.f, (_Float16)0.f,
                       (_Float16)0.f, (_Float16)0.f, (_Float16)0.f, (_Float16)0.f};
            if (ix - lo < uslice)        // exec-masked: only active lanes issue
                a = h1[ix];              // 16 B gather IS the A-fragment
            half8 b = Btab[s * 64 + lane];
            acc = __builtin_amdgcn_mfma_f32_16x16x32_f16(a, b, acc, 0, 0, 0);
        }
    }

    // C/D: col=lane&15 (=d), row=q*4+reg (=n). relu * w_out, 16-lane col sum.
    float wo = (m < CH) ? w_out[m] : 0.f;
    float v0 = fmaxf(acc[0], 0.f) * wo, v1 = fmaxf(acc[1], 0.f) * wo;
    float v2 = fmaxf(acc[2], 0.f) * wo, v3 = fmaxf(acc[3], 0.f) * wo;
#pragma unroll
    for (int off = 1; off < 16; off <<= 1) {
        v0 += __shfl_xor(v0, off, 16);
        v1 += __shfl_xor(v1, off, 16);
        v2 += __shfl_xor(v2, off, 16);
        v3 += __shfl_xor(v3, off, 16);
    }
    if (m == 0) {
        int gn = n0 + wid * 16 + q * 4;
        if (gn + 0 < n_total) outf[gn + 0] = v0;
        if (gn + 1 < n_total) outf[gn + 1] = v1;
        if (gn + 2 < n_total) outf[gn + 2] = v2;
        if (gn + 3 < n_total) outf[gn + 3] = v3;
    }
}

// ---------------- k_fin: dense election -> float ----------------------------
__global__ __launch_bounds__(256) void k_fin(const float* __restrict__ outf,
                                             int* cells, float* cellsf,
                                             int n_cells4, int n_total) {
    int i = blockIdx.x * blockDim.x + threadIdx.x;
    if (i >= n_cells4) return;
    int4 v = ((const int4*)cells)[i];
    float4 r;
    r.x = (v.x >= 1 && v.x <= n_total) ? outf[v.x - 1] : 0.f;
    r.y = (v.y >= 1 && v.y <= n_total) ? outf[v.y - 1] : 0.f;
    r.z = (v.z >= 1 && v.z <= n_total) ? outf[v.z - 1] : 0.f;
    r.w = (v.w >= 1 && v.w <= n_total) ? outf[v.w - 1] : 0.f;
    ((float4*)cellsf)[i] = r;
}

extern "C" void kernel_launch(void* const* d_in, const int* in_sizes, int n_in,
                              void* d_out, int out_size, void* d_ws, size_t ws_size,
                              hipStream_t stream) {
    const float* w1       = (const float*)d_in[1];
    const float* w2       = (const float*)d_in[2];
    const float* w_out    = (const float*)d_in[3];
    const int*   nbr_idx  = (const int*)d_in[4];
    const int*   nbr_mask = (const int*)d_in[5];
    const int*   coords   = (const int*)d_in[6];
    const int*   batch    = (const int*)d_in[7];

    int n_total = in_sizes[0];
    int npad = (n_total + 63) & ~63;
    int nc4 = out_size / 4;

    // ws: h1 (N+1 half8) | bitsT (3*npad u32) | outf (npad f32) | Btab
    half8*    h1    = (half8*)d_ws;
    unsigned* bitsT = (unsigned*)((char*)d_ws + (size_t)(n_total + 1) * sizeof(half8));
    float*    outf  = (float*)((char*)bitsT + (size_t)3 * npad * sizeof(unsigned));
    half8*    Btab  = (half8*)(outf + npad);
    float*    out   = (float*)d_out;

    int nb64 = (n_total + 63) / 64;     // 2344 blocks: grid-parity, high occ
    k_h1b<<<nb64, 256, 0, stream>>>(w1, w2, nbr_mask, coords, batch,
                                    h1, bitsT, Btab, (int*)out, n_total, npad);
    k_h2m<<<nb64, 256, 0, stream>>>(h1, Btab, nbr_idx, bitsT, w_out, outf,
                                    n_total, npad);
    k_fin<<<(nc4 + 255) / 256, 256, 0, stream>>>(outf, (int*)out, out, nc4, n_total);
}